// Round 6
// baseline (159.775 us; speedup 1.0000x reference)
//
#include <hip/hip_runtime.h>
#include <hip/hip_bf16.h>
#include <stdint.h>

// Problem constants (from reference)
#define B_N     2048
#define E_N     32
#define IN_N    2048
#define OUT_N   1024
#define TOPK    4

// GEMM tiling
#define BM      256
#define BN      256
#define BK      32
#define NT      (OUT_N / BN)        // 4 n-tiles
#define NKT     (IN_N / BK)         // 64 k-steps
#define THREADS 512                 // 8 waves, 2m x 4n, wave tile 128x64
#define MAX_SLOTS 64                // sum ceil(c_e/256) <= 8192/256+32 = 64
#define GRID_GEMM (MAX_SLOTS * NT)  // 256

// ws layout
#define WS_COUNTS 0     // [32] ints
#define WS_NSLOTS 32    // [1]
#define WS_DESC   64    // [MAX_SLOTS] packed (e<<6)|mt
#define WS_LISTS  256   // [E_N][B_N] packed (b<<2)|k
#define FEATB_OFF 264192  // byte offset of bf16 feat copy (16B aligned), 8MB

typedef float  f32x4  __attribute__((ext_vector_type(4)));
typedef __bf16 bf16x8 __attribute__((ext_vector_type(8)));

union Pack8 { bf16x8 v; uint4 u; };

__device__ __forceinline__ uint4 pack8(f32x4 lo, f32x4 hi) {
  Pack8 p;
#pragma unroll
  for (int j = 0; j < 4; ++j) { p.v[j] = (__bf16)lo[j]; p.v[j + 4] = (__bf16)hi[j]; }
  return p.u;
}
__device__ __forceinline__ bf16x8 as_frag(uint4 u) { Pack8 p; p.u = u; return p.v; }

__device__ __forceinline__ void glds16(const void* g, const uint4* l) {
  __builtin_amdgcn_global_load_lds(
      (const __attribute__((address_space(1))) void*)g,
      (__attribute__((address_space(3))) void*)l, 16, 0, 0);
}

// ---------------- kernel 0: zero counters ----------------
__global__ void k_zero(int* __restrict__ ws) {
  if (threadIdx.x < 64) ws[threadIdx.x] = 0;
}

// ---------------- kernel 0b: feat f32 -> bf16 copy ----------------
__global__ void k_conv(const float* __restrict__ f, unsigned short* __restrict__ o) {
  int i = (blockIdx.x * 256 + threadIdx.x) * 8;
  f32x4 a = *(const f32x4*)(f + i);
  f32x4 b = *(const f32x4*)(f + i + 4);
  *(uint4*)(o + i) = pack8(a, b);
}

// ---------------- kernel 1: top-4-smallest + bucket ----------------
__global__ void k_topk(const float* __restrict__ act, int* __restrict__ ws) {
  int b = blockIdx.x * blockDim.x + threadIdx.x;
  if (b >= B_N) return;
  float v[E_N];
  const float* a = act + (size_t)b * E_N;
#pragma unroll
  for (int e = 0; e < E_N; ++e) v[e] = a[e];
  unsigned chosen = 0;
#pragma unroll
  for (int k = 0; k < TOPK; ++k) {
    float mv = 3.4e38f; int mi = 0;
#pragma unroll
    for (int e = 0; e < E_N; ++e) {
      bool sel = (((chosen >> e) & 1u) == 0u) && (v[e] < mv);  // strict <: stable
      mv = sel ? v[e] : mv;
      mi = sel ? e : mi;
    }
    chosen |= (1u << mi);
    int pos = atomicAdd(&ws[WS_COUNTS + mi], 1);
    ws[WS_LISTS + mi * B_N + pos] = (b << 2) | k;
  }
}

// ---------------- kernel 2: build tile worklist ----------------
__global__ void k_tiles(int* __restrict__ ws) {
  int e = threadIdx.x;  // one wave
  int c = (e < E_N) ? ws[WS_COUNTS + e] : 0;
  int t = (c + BM - 1) / BM;
  int off = 0, tot = 0;
  for (int j = 0; j < E_N; ++j) {
    int tj = __shfl(t, j, 64);
    if (j < e) off += tj;
    tot += tj;
  }
  if (e < E_N) {
    for (int i = 0; i < t; ++i) ws[WS_DESC + off + i] = (e << 6) | i;
  }
  if (e == 0) ws[WS_NSLOTS] = tot;
}

// ---------------- kernel 3: grouped GEMM, counted-vmcnt pipeline ----------------
// 256x256 tile, BK=32. A: bf16 via global_load_lds, triple-buffered, depth-2.
// W: f32 reg-staged 2-deep (rwA/rwB), packed to bf16 LDS, double-buffered.
// Raw s_barrier + s_waitcnt vmcnt(6): 6 loads/wave (2 A-glds + 4 W) stay in
// flight across every barrier. LDS 80KB -> 2 blocks/CU.
__global__ __launch_bounds__(THREADS, 2)
void k_gemm(const unsigned short* __restrict__ featb, const float* __restrict__ Wm,
            const float* __restrict__ bias, const int* __restrict__ ws,
            float* __restrict__ out) {
  int p = blockIdx.x;
  int x = p & 7, j = p >> 3;
  int slot = x + 8 * (j >> 2);   // slot % 8 == XCD
  int nt   = j & 3;
  if (slot >= ws[WS_NSLOTS]) return;
  int desc = ws[WS_DESC + slot];
  int e = desc >> 6, mt = desc & 63;
  int count = ws[WS_COUNTS + e];
  int m0 = mt * BM;

  // LDS: A bufs 0..2 at [0,3072), W bufs 0..1 at [3072,5120)  (uint4 units)
  __shared__ uint4 lds4[5120];

  int tid  = threadIdx.x;
  int lane = tid & 63;
  int wv   = tid >> 6;
  int wm   = wv >> 2;   // 0..1
  int wn   = wv & 3;    // 0..3

  // --- A glds sources: 2 instrs/wave; lane handles LDS slot wv*128 + i*64 + lane ---
  const unsigned short* asrc0;
  const unsigned short* asrc1;
  {
    int s0 = wv * 128 + lane,      r0 = s0 >> 2, t0 = s0 & 3;
    int s1 = wv * 128 + 64 + lane, r1 = s1 >> 2, t1 = s1 & 3;
    int g0 = (m0 + r0 < count) ? (ws[WS_LISTS + e * B_N + m0 + r0] >> 2) : 0;
    int g1 = (m0 + r1 < count) ? (ws[WS_LISTS + e * B_N + m0 + r1] >> 2) : 0;
    asrc0 = featb + (size_t)g0 * IN_N + ((t0 ^ ((r0 >> 1) & 3)) * 8);
    asrc1 = featb + (size_t)g1 * IN_N + ((t1 ^ ((r1 >> 1) & 3)) * 8);
  }

  // --- W staging: row = tid>>1, half = tid&1 (16 floats) ---
  int wrow = tid >> 1, half = tid & 1;
  const float* wp = Wm + ((size_t)e * OUT_N + (size_t)(nt * BN + wrow)) * IN_N + half * 16;
  int wswz = (wrow >> 1) & 3;
  int wsl0 = wrow * 4 + ((half * 2) ^ wswz);
  int wsl1 = wrow * 4 + ((half * 2 + 1) ^ wswz);

  // --- fragment read indices (relative, uint4 units) ---
  int aidx[8], bidx[4];
#pragma unroll
  for (int mi = 0; mi < 8; ++mi) {
    int r = wm * 128 + mi * 16 + (lane & 15);
    aidx[mi] = r * 4 + ((lane >> 4) ^ ((r >> 1) & 3));
  }
#pragma unroll
  for (int ni = 0; ni < 4; ++ni) {
    int r = wn * 64 + ni * 16 + (lane & 15);
    bidx[ni] = r * 4 + ((lane >> 4) ^ ((r >> 1) & 3));
  }

  f32x4 rwA[4], rwB[4];
  f32x4 acc[8][4] = {};

#define AGLDS(K2, AB)                                                         \
  do {                                                                        \
    glds16(asrc0 + (size_t)(K2) * BK, &lds4[(AB) * 1024 + wv * 128]);         \
    glds16(asrc1 + (size_t)(K2) * BK, &lds4[(AB) * 1024 + wv * 128 + 64]);    \
  } while (0)

#define WLOAD(K2, RW)                                                         \
  do {                                                                        \
    RW[0] = *(const f32x4*)(wp + (size_t)(K2) * BK);                          \
    RW[1] = *(const f32x4*)(wp + (size_t)(K2) * BK + 4);                      \
    RW[2] = *(const f32x4*)(wp + (size_t)(K2) * BK + 8);                      \
    RW[3] = *(const f32x4*)(wp + (size_t)(K2) * BK + 12);                     \
  } while (0)

#define WPACK(RW, WB)                                                         \
  do {                                                                        \
    lds4[3072 + (WB) * 1024 + wsl0] = pack8(RW[0], RW[1]);                    \
    lds4[3072 + (WB) * 1024 + wsl1] = pack8(RW[2], RW[3]);                    \
  } while (0)

#define MFMAS(AB, WB)                                                         \
  do {                                                                        \
    bf16x8 af[8], bfr[4];                                                     \
    _Pragma("unroll")                                                         \
    for (int ni = 0; ni < 4; ++ni)                                            \
      bfr[ni] = as_frag(lds4[3072 + (WB) * 1024 + bidx[ni]]);                 \
    _Pragma("unroll")                                                         \
    for (int mi = 0; mi < 8; ++mi) af[mi] = as_frag(lds4[(AB) * 1024 + aidx[mi]]); \
    _Pragma("unroll")                                                         \
    for (int mi = 0; mi < 8; ++mi)                                            \
      _Pragma("unroll")                                                       \
      for (int ni = 0; ni < 4; ++ni)                                          \
        acc[mi][ni] = __builtin_amdgcn_mfma_f32_16x16x32_bf16(af[mi], bfr[ni], acc[mi][ni], 0, 0, 0); \
  } while (0)

#define WAITVM(N)                                                             \
  asm volatile("s_waitcnt vmcnt(" #N ")" ::: "memory");                       \
  __builtin_amdgcn_sched_barrier(0)

#define BARRIER()                                                             \
  asm volatile("s_waitcnt lgkmcnt(0)" ::: "memory");                          \
  __builtin_amdgcn_sched_barrier(0);                                          \
  __builtin_amdgcn_s_barrier()

  // ---- prologue: A(0)->buf0, A(1)->buf1, W(0)->rwA, W(1)->rwB ----
  AGLDS(0, 0);
  AGLDS(1, 1);
  WLOAD(0, rwA);
  WLOAD(1, rwB);
  WAITVM(4);            // A0,A1,W0 done; W1 (newest 4) may fly
  WPACK(rwA, 0);
  BARRIER();

  // ---- main loop: steps kt and kt+1, always full-issue (kt+3 <= 63) ----
  int ab = 0;  // = kt % 3
#pragma unroll 1
  for (int kt = 0; kt < NKT - 2; kt += 2) {
    {  // even step kt: compute (ab, W0); pack W(kt+1)=rwB -> W1; issue kt+2 -> rwA
      int ab2 = (ab == 0) ? 2 : ab - 1;          // (kt+2)%3
      AGLDS(kt + 2, ab2);
      WLOAD(kt + 2, rwA);
      MFMAS(ab, 0);
      WAITVM(6);
      WPACK(rwB, 1);
      BARRIER();
    }
    {  // odd step kt+1: compute (ab+1, W1); pack W(kt+2)=rwA -> W0; issue kt+3 -> rwB
      int abo = (ab == 2) ? 0 : ab + 1;          // (kt+1)%3
      int ab2 = (abo == 0) ? 2 : abo - 1;        // (kt+3)%3
      AGLDS(kt + 3, ab2);
      WLOAD(kt + 3, rwB);
      MFMAS(abo, 1);
      WAITVM(6);
      WPACK(rwA, 0);
      BARRIER();
    }
    ab = (ab == 1) ? 0 : ((ab == 2) ? 1 : 2);    // ab = (ab+2)%3
  }

  // ---- epilogue: step 62 (ab=2, W0), pack W63; step 63 (ab=0, W1) ----
  MFMAS(2, 0);
  WAITVM(0);
  WPACK(rwB, 1);
  BARRIER();
  MFMAS(0, 1);

  // ---- store: D row=(lane>>4)*4+j, col=lane&15 ----
#pragma unroll
  for (int ni = 0; ni < 4; ++ni) {
    int col = nt * BN + wn * 64 + ni * 16 + (lane & 15);
    float bs = bias[e * OUT_N + col];
#pragma unroll
    for (int mi = 0; mi < 8; ++mi) {
#pragma unroll
      for (int j2 = 0; j2 < 4; ++j2) {
        int row = wm * 128 + mi * 16 + (lane >> 4) * 4 + j2;
        if (m0 + row < count) {
          int g = ws[WS_LISTS + e * B_N + m0 + row];
          out[(size_t)g * OUT_N + col] = acc[mi][ni][j2] + bs;
        }
      }
    }
  }
}

extern "C" void kernel_launch(void* const* d_in, const int* in_sizes, int n_in,
                              void* d_out, int out_size, void* d_ws, size_t ws_size,
                              hipStream_t stream) {
  const float* feat = (const float*)d_in[0];   // [B, IN]
  const float* Wm   = (const float*)d_in[1];   // [E, OUT, IN]
  const float* bias = (const float*)d_in[2];   // [E, OUT]
  const float* act  = (const float*)d_in[3];   // [B, E]
  int*   ws  = (int*)d_ws;
  unsigned short* featb = (unsigned short*)((char*)d_ws + FEATB_OFF);
  float* out = (float*)d_out;

  hipLaunchKernelGGL(k_zero,  dim3(1),                  dim3(64),      0, stream, ws);
  hipLaunchKernelGGL(k_conv,  dim3(B_N * IN_N / 2048),  dim3(256),     0, stream, feat, featb);
  hipLaunchKernelGGL(k_topk,  dim3(B_N / 256),          dim3(256),     0, stream, act, ws);
  hipLaunchKernelGGL(k_tiles, dim3(1),                  dim3(64),      0, stream, ws);
  hipLaunchKernelGGL(k_gemm,  dim3(GRID_GEMM),          dim3(THREADS), 0, stream,
                     featb, Wm, bias, ws, out);
}